// Round 15
// baseline (178.153 us; speedup 1.0000x reference)
//
#include <hip/hip_runtime.h>
#include <stdint.h>

typedef unsigned short u16;
typedef __bf16 bfx8 __attribute__((ext_vector_type(8)));
typedef float f32x4 __attribute__((ext_vector_type(4)));

__device__ __forceinline__ u16 f2bf(float x) {
    unsigned int u = __float_as_uint(x);
    u += 0x7fffu + ((u >> 16) & 1u);
    return (u16)(u >> 16);
}
__device__ __forceinline__ float bf2f(u16 v) {
    return __uint_as_float(((unsigned)v) << 16);
}

__device__ __forceinline__ void async16(const void* g, void* l) {
    __builtin_amdgcn_global_load_lds(
        (const __attribute__((address_space(1))) unsigned int*)(uintptr_t)g,
        (__attribute__((address_space(3))) unsigned int*)(unsigned int)(uintptr_t)l,
        16, 0, 0);
}

#define S_BARRIER() asm volatile("s_barrier" ::: "memory")
#define WAIT_VM6() asm volatile("s_waitcnt vmcnt(6)" ::: "memory")
#define WAIT_VM5() asm volatile("s_waitcnt vmcnt(5)" ::: "memory")
#define WAIT_VM0() asm volatile("s_waitcnt vmcnt(0)" ::: "memory")

// ---------------------------------------------------------------------------
// fused cast: 7 segments of f32 -> bf16, 8 elems/thread, one launch
// ---------------------------------------------------------------------------
struct CastArgs {
    const float* src[7];
    u16* dst[7];
    int nblk[7];
};
__global__ __launch_bounds__(256) void cast_all(CastArgs a) {
    int b = blockIdx.x, seg = 0;
    while (b >= a.nblk[seg]) { b -= a.nblk[seg]; ++seg; }
    int i = b * 256 + threadIdx.x;
    const float4* p = (const float4*)(a.src[seg] + (size_t)i * 8);
    float4 x = p[0], y = p[1];
    ushort4 o0, o1;
    o0.x = f2bf(x.x); o0.y = f2bf(x.y); o0.z = f2bf(x.z); o0.w = f2bf(x.w);
    o1.x = f2bf(y.x); o1.y = f2bf(y.y); o1.z = f2bf(y.z); o1.w = f2bf(y.w);
    ushort4* q = (ushort4*)(a.dst[seg] + (size_t)i * 8);
    q[0] = o0; q[1] = o1;
}

// ---------------------------------------------------------------------------
// m97-structure GEMM for QKV: 128x128 tile, BK=64, 256 threads = 4 waves,
// single 32KB LDS, 2-barrier loop, XOR-8 swizzle both sides.
// launch_bounds(256,4): VGPR 60 ((256,5) forced spill — register cliff, r12).
// ROUND-15: XCD chunk axis transposed — each XCD owns a COLUMN band
// (3 col-blocks x all 64 row-blocks) so its B panel (384x1024 bf16 = 768KB)
// is L2-resident; previously each XCD touched full B (6MB > 4MB L2) and
// FETCH was 73MB vs 22 ideal. A streams once, L3-served across XCDs.
// Epilogue: cols 0-1023 Q / 1024-2047 K / 2048-3071 V^T.
// ---------------------------------------------------------------------------
__global__ __launch_bounds__(256, 4)
void gemm97_qkv(const u16* __restrict__ A, const u16* __restrict__ Bw,
                u16* __restrict__ outq, u16* __restrict__ outk,
                u16* __restrict__ vt, int K, int nrow) {
    __shared__ __align__(1024) unsigned char lds[32768];
    const int t = threadIdx.x;
    const int lane = t & 63, w = t >> 6;
    const int laneR = lane & 15, laneK = lane >> 4;
    const int wr = w >> 1, wc = w & 1;
    const int b = blockIdx.x;
    const int cpx = gridDim.x >> 3;
    const int swz = (b & 7) * cpx + (b >> 3);
    // column-band per XCD: row fastest within a col-block
    const int row0 = (swz % nrow) * 128, col0 = (swz / nrow) * 128;
    const int nt = K >> 6;

    f32x4 acc[4][4] = {};

    const u16* srcA[4];
    const u16* srcB[4];
    unsigned dA[4], dB[4];
#pragma unroll
    for (int i = 0; i < 4; ++i) {
        int li = i * 256 + t;
        int row = li >> 3, ko = li & 7;
        int kos = (ko ^ (row & 7)) * 8;
        srcA[i] = A + (size_t)(row0 + row) * K + kos;
        srcB[i] = Bw + (size_t)(col0 + row) * K + kos;
        dA[i] = li * 16;
        dB[i] = 16384 + li * 16;
    }

    for (int tk = 0; tk < nt; ++tk) {
        const int o = tk * 64;
#pragma unroll
        for (int i = 0; i < 4; ++i) {
            async16(srcA[i] + o, lds + dA[i]);
            async16(srcB[i] + o, lds + dB[i]);
        }
        __syncthreads();
#pragma unroll
        for (int ks = 0; ks < 2; ++ks) {
            bfx8 af[4], bf[4];
#pragma unroll
            for (int m = 0; m < 4; ++m) {
                int r = wr * 64 + m * 16 + laneR;
                int ph = (ks * 4 + laneK) ^ (r & 7);
                af[m] = *(const bfx8*)(lds + r * 128 + ph * 16);
            }
#pragma unroll
            for (int n = 0; n < 4; ++n) {
                int r = wc * 64 + n * 16 + laneR;
                int ph = (ks * 4 + laneK) ^ (r & 7);
                bf[n] = *(const bfx8*)(lds + 16384 + r * 128 + ph * 16);
            }
#pragma unroll
            for (int m = 0; m < 4; ++m)
#pragma unroll
                for (int n = 0; n < 4; ++n)
                    acc[m][n] = __builtin_amdgcn_mfma_f32_16x16x32_bf16(
                        af[m], bf[n], acc[m][n], 0, 0, 0);
        }
        __syncthreads();
    }

#pragma unroll
    for (int m = 0; m < 4; ++m) {
        const int gr0 = row0 + wr * 64 + m * 16 + laneK * 4;
#pragma unroll
        for (int n = 0; n < 4; ++n) {
            const int gc = col0 + wc * 64 + n * 16 + laneR;
            if (col0 < 1024) {
#pragma unroll
                for (int r = 0; r < 4; ++r)
                    outq[(size_t)(gr0 + r) * 1024 + gc] = f2bf(acc[m][n][r]);
            } else if (col0 < 2048) {
#pragma unroll
                for (int r = 0; r < 4; ++r)
                    outk[(size_t)(gr0 + r) * 1024 + (gc - 1024)] = f2bf(acc[m][n][r]);
            } else {
                ushort4 o4;
                o4.x = f2bf(acc[m][n][0]); o4.y = f2bf(acc[m][n][1]);
                o4.z = f2bf(acc[m][n][2]); o4.w = f2bf(acc[m][n][3]);
                *(ushort4*)(vt + (((size_t)(gr0 >> 12)) * 1024 + (gc - 2048)) * 4096 +
                            (gr0 & 4095)) = o4;
            }
        }
    }
}

// ---------------------------------------------------------------------------
// RING GEMM (r8/r10 4-barrier variant, measured best for Wo/W1/W2):
// BM=256, BN=BNv(128|64), BK=64, 8 waves (4M x 2N), wave tile 64 x BNv/2.
// 3-deep LDS ring, depth-2 prefetch, counted vmcnt(6|5) folded into the
// ks1 end-barrier. XCD-chunked bijective 1D grid swizzle (B panels <= 2MB,
// already L2-resident — no axis transpose needed here).
// EPI 1: draftb = bf16(bf2f(resb) + C)
// EPI 2 (BN=64): outb = bf16(gelu(C + bias))
// EPI 3: outf = bf2f(draftb) + C + bias
// ---------------------------------------------------------------------------
template <int EPI, int BNv>
__global__ __launch_bounds__(512, 2)
void gemm_ring(const u16* __restrict__ A, const u16* __restrict__ Bw,
               u16* __restrict__ outb, const float* __restrict__ bias,
               const u16* __restrict__ resb, u16* __restrict__ draftb,
               float* __restrict__ outf, int M, int N, int K, int ncol) {
    constexpr int NF = BNv / 32;
    constexpr int BU = BNv / 64;
    constexpr int TS = 32768 + BNv * 128;
    __shared__ __align__(1024) unsigned char lds[3 * TS];
    const int t = threadIdx.x;
    const int lane = t & 63, w = t >> 6;
    const int laneR = lane & 15, laneK = lane >> 4;
    const int wr = w >> 1, wc = w & 1;
    const int b = blockIdx.x;
    const int cpx = gridDim.x >> 3;
    const int swz = (b & 7) * cpx + (b >> 3);
    const int row0 = (swz / ncol) * 256, col0 = (swz % ncol) * BNv;
    const int nt = K >> 6;

    f32x4 acc[4][NF] = {};

    const u16* srcA[4];
    const u16* srcB[BU];
    unsigned dA[4], dB[BU];
#pragma unroll
    for (int i = 0; i < 4; ++i) {
        int li = i * 512 + t;
        int row = li >> 3, ko = li & 7;
        srcA[i] = A + (size_t)(row0 + row) * K + (ko ^ (row & 7)) * 8;
        dA[i] = li * 16;
    }
#pragma unroll
    for (int i = 0; i < BU; ++i) {
        int li = i * 512 + t;
        int row = li >> 3, ko = li & 7;
        srcB[i] = Bw + (size_t)(col0 + row) * K + (ko ^ (row & 7)) * 8;
        dB[i] = 32768 + li * 16;
    }

    auto stage = [&](int rb, int tk, int h) {
        unsigned char* base = lds + rb * TS;
        const int o = tk * 64;
        if (h == 0) {
            async16(srcA[0] + o, base + dA[0]);
            async16(srcA[1] + o, base + dA[1]);
            async16(srcB[0] + o, base + dB[0]);
        } else {
            async16(srcA[2] + o, base + dA[2]);
            async16(srcA[3] + o, base + dA[3]);
            if constexpr (BU == 2) async16(srcB[1] + o, base + dB[1]);
        }
    };

    stage(0, 0, 0); stage(0, 0, 1);
    stage(1, 1, 0); stage(1, 1, 1);
    if constexpr (BU == 2) { WAIT_VM6(); } else { WAIT_VM5(); }
    S_BARRIER();

    for (int tk = 0; tk < nt; ++tk) {
        unsigned char* bufA = lds + (tk % 3) * TS;
        unsigned char* bufB = bufA + 32768;
        const bool pf = (tk + 2 < nt);
        const int nb = (tk + 2) % 3;
#pragma unroll
        for (int ks = 0; ks < 2; ++ks) {
            bfx8 af[4], bf[NF];
#pragma unroll
            for (int m = 0; m < 4; ++m) {
                int r = wr * 64 + m * 16 + laneR;
                int phys = (ks * 4 + laneK) ^ (r & 7);
                af[m] = *(const bfx8*)(bufA + r * 128 + phys * 16);
            }
#pragma unroll
            for (int n = 0; n < NF; ++n) {
                int r = wc * (BNv / 2) + n * 16 + laneR;
                int phys = (ks * 4 + laneK) ^ (r & 7);
                bf[n] = *(const bfx8*)(bufB + r * 128 + phys * 16);
            }
            if (pf) stage(nb, tk + 2, ks);
            S_BARRIER();
            __builtin_amdgcn_s_setprio(1);
#pragma unroll
            for (int m = 0; m < 4; ++m)
#pragma unroll
                for (int n = 0; n < NF; ++n)
                    acc[m][n] = __builtin_amdgcn_mfma_f32_16x16x32_bf16(
                        af[m], bf[n], acc[m][n], 0, 0, 0);
            __builtin_amdgcn_s_setprio(0);
            if (ks == 1) {
                if (pf) {
                    if constexpr (BU == 2) { WAIT_VM6(); } else { WAIT_VM5(); }
                } else {
                    WAIT_VM0();
                }
            }
            S_BARRIER();
        }
    }

#pragma unroll
    for (int m = 0; m < 4; ++m) {
        const int gr0 = row0 + wr * 64 + m * 16 + laneK * 4;
#pragma unroll
        for (int n = 0; n < NF; ++n) {
            const int gc = col0 + wc * (BNv / 2) + n * 16 + laneR;
            if constexpr (EPI == 1) {
#pragma unroll
                for (int r = 0; r < 4; ++r) {
                    size_t idx = (size_t)(gr0 + r) * N + gc;
                    draftb[idx] = f2bf(bf2f(resb[idx]) + acc[m][n][r]);
                }
            } else if constexpr (EPI == 2) {
#pragma unroll
                for (int r = 0; r < 4; ++r) {
                    float xx = acc[m][n][r] + bias[gc];
                    outb[(size_t)(gr0 + r) * N + gc] =
                        f2bf(xx * 0.5f * (1.0f + erff(xx * 0.70710678118654752f)));
                }
            } else {
#pragma unroll
                for (int r = 0; r < 4; ++r) {
                    size_t idx = (size_t)(gr0 + r) * N + gc;
                    outf[idx] = bf2f(draftb[idx]) + acc[m][n][r] + bias[gc];
                }
            }
        }
    }
}

// ---------------------------------------------------------------------------
// banded attention: WINDOW=32, 32-query tiles, 64-key band [i0-32, i0+31].
// 512 threads / 8 waves per block (r14; perf equal to 256-thread variant).
// ---------------------------------------------------------------------------
__global__ __launch_bounds__(512)
void attn_kernel(const u16* __restrict__ Q, const u16* __restrict__ K,
                 const u16* __restrict__ vt, u16* __restrict__ O) {
    constexpr int H = 1024, S = 4096;
    const int t = threadIdx.x, lane = t & 63, w = t >> 6;
    const int laneR = lane & 15, laneK = lane >> 4;
    const int bb = blockIdx.x;
    const int tile = (bb & 7) * 32 + (bb >> 3);
    const int batch = tile >> 7;
    const int i0 = (tile & 127) * 32;
    const size_t base = (size_t)batch * S * H;

    __shared__ __align__(16) float S4[8][32][68];
    __shared__ __align__(16) u16 P[32][72];

    f32x4 sc[2][4] = {};
    for (int h = w * 128; h < w * 128 + 128; h += 32) {
        bfx8 qa[2];
#pragma unroll
        for (int m = 0; m < 2; ++m) {
            size_t row = (size_t)(i0 + m * 16 + laneR);
            qa[m] = *(const bfx8*)(Q + base + row * H + h + laneK * 8);
        }
        bfx8 kb[4];
#pragma unroll
        for (int n = 0; n < 4; ++n) {
            int j = i0 - 32 + n * 16 + laneR;
            int jc = j < 0 ? 0 : j;
            kb[n] = *(const bfx8*)(K + base + (size_t)jc * H + h + laneK * 8);
        }
#pragma unroll
        for (int m = 0; m < 2; ++m)
#pragma unroll
            for (int n = 0; n < 4; ++n)
                sc[m][n] = __builtin_amdgcn_mfma_f32_16x16x32_bf16(
                    qa[m], kb[n], sc[m][n], 0, 0, 0);
    }
#pragma unroll
    for (int m = 0; m < 2; ++m)
#pragma unroll
        for (int n = 0; n < 4; ++n)
#pragma unroll
            for (int r = 0; r < 4; ++r)
                S4[w][m * 16 + laneK * 4 + r][n * 16 + laneR] = sc[m][n][r];
    __syncthreads();

    {
        int q = t >> 4;
        int c0 = (t & 15) * 4;
        int lo = q + 1;
        if (32 - i0 > lo) lo = 32 - i0;
        int hi = q + 32;
        float vals[4];
        float mx = -1e30f;
#pragma unroll
        for (int c = 0; c < 4; ++c) {
            int cc = c0 + c;
            float v = 0.f;
#pragma unroll
            for (int p = 0; p < 8; ++p) v += S4[p][q][cc];
            v *= 0.03125f;
            bool valid = (cc >= lo) && (cc <= hi);
            vals[c] = valid ? v : -1e30f;
            if (vals[c] > mx) mx = vals[c];
        }
#pragma unroll
        for (int d = 1; d < 16; d <<= 1) {
            float o = __shfl_xor(mx, d);
            if (o > mx) mx = o;
        }
        float sum = 0.f;
        float es[4];
#pragma unroll
        for (int c = 0; c < 4; ++c) {
            es[c] = (vals[c] > -1e29f) ? __expf(vals[c] - mx) : 0.f;
            sum += es[c];
        }
#pragma unroll
        for (int d = 1; d < 16; d <<= 1) sum += __shfl_xor(sum, d);
        float inv = 1.0f / sum;
#pragma unroll
        for (int c = 0; c < 4; ++c) P[q][c0 + c] = f2bf(es[c] * inv);
    }
    __syncthreads();

    for (int nc = 0; nc < 2; ++nc) {
        int ncol = w * 128 + nc * 64;
        f32x4 o[2][4] = {};
#pragma unroll
        for (int ks = 0; ks < 2; ++ks) {
            bfx8 pa[2];
#pragma unroll
            for (int m = 0; m < 2; ++m)
                pa[m] = *(const bfx8*)(&P[m * 16 + laneR][ks * 32 + laneK * 8]);
            int t0 = i0 - 32 + ks * 32 + laneK * 8;
            if (t0 < 0) t0 = 0;
#pragma unroll
            for (int n = 0; n < 4; ++n) {
                int c = ncol + n * 16 + laneR;
                bfx8 vb = *(const bfx8*)(vt + ((size_t)batch * 1024 + c) * 4096 + t0);
#pragma unroll
                for (int m = 0; m < 2; ++m)
                    o[m][n] = __builtin_amdgcn_mfma_f32_16x16x32_bf16(
                        pa[m], vb, o[m][n], 0, 0, 0);
            }
        }
#pragma unroll
        for (int m = 0; m < 2; ++m)
#pragma unroll
            for (int n = 0; n < 4; ++n)
#pragma unroll
                for (int r = 0; r < 4; ++r) {
                    size_t row = (size_t)(i0 + m * 16 + laneK * 4 + r);
                    O[base + row * H + ncol + n * 16 + laneR] = f2bf(o[m][n][r]);
                }
    }
}

// ---------------------------------------------------------------------------
// LayerNorm over H=1024, one block per row, bf16 in -> bf16 out
// ---------------------------------------------------------------------------
__global__ __launch_bounds__(256)
void ln_kernel(const u16* __restrict__ xb, const float* __restrict__ gw,
               const float* __restrict__ gb, u16* __restrict__ out) {
    const int row = blockIdx.x, t = threadIdx.x;
    const ushort4 dv = ((const ushort4*)(xb + (size_t)row * 1024))[t];
    float4 v;
    v.x = bf2f(dv.x); v.y = bf2f(dv.y); v.z = bf2f(dv.z); v.w = bf2f(dv.w);
    float s = v.x + v.y + v.z + v.w;
    float s2 = v.x * v.x + v.y * v.y + v.z * v.z + v.w * v.w;
#pragma unroll
    for (int d = 1; d < 64; d <<= 1) {
        s += __shfl_xor(s, d);
        s2 += __shfl_xor(s2, d);
    }
    __shared__ float red[8];
    int lane = t & 63, wv = t >> 6;
    if (lane == 0) { red[wv] = s; red[4 + wv] = s2; }
    __syncthreads();
    float S1 = red[0] + red[1] + red[2] + red[3];
    float S2 = red[4] + red[5] + red[6] + red[7];
    float mu = S1 * (1.0f / 1024.0f);
    float var = S2 * (1.0f / 1024.0f) - mu * mu;
    float rstd = rsqrtf(var + 1e-5f);
    const float4 wv4 = ((const float4*)gw)[t];
    const float4 bv4 = ((const float4*)gb)[t];
    ushort4 o;
    o.x = f2bf((v.x - mu) * rstd * wv4.x + bv4.x);
    o.y = f2bf((v.y - mu) * rstd * wv4.y + bv4.y);
    o.z = f2bf((v.z - mu) * rstd * wv4.z + bv4.z);
    o.w = f2bf((v.w - mu) * rstd * wv4.w + bv4.w);
    ((ushort4*)(out + (size_t)row * 1024))[t] = o;
}

// ---------------------------------------------------------------------------
extern "C" void kernel_launch(void* const* d_in, const int* in_sizes, int n_in,
                              void* d_out, int out_size, void* d_ws, size_t ws_size,
                              hipStream_t stream) {
    const float* x   = (const float*)d_in[0];
    const float* Wq  = (const float*)d_in[1];
    const float* Wk  = (const float*)d_in[2];
    const float* Wv  = (const float*)d_in[3];
    const float* Wo  = (const float*)d_in[4];
    const float* lnw = (const float*)d_in[5];
    const float* lnb = (const float*)d_in[6];
    const float* W1  = (const float*)d_in[7];
    const float* b1  = (const float*)d_in[8];
    const float* W2  = (const float*)d_in[9];
    const float* b2  = (const float*)d_in[10];
    (void)in_sizes; (void)n_in; (void)out_size; (void)ws_size;

    const int M = 8192, H = 1024, Hh = 512;

    char* ws = (char*)d_ws;
    size_t off = 0;
    auto alloc = [&](size_t bytes) {
        char* p = ws + off;
        off += (bytes + 255) & ~(size_t)255;
        return p;
    };
    u16* Xb     = (u16*)alloc((size_t)M * H * 2);      // residual for Wo
    u16* Wqkvb  = (u16*)alloc((size_t)3 * H * H * 2);
    u16* Wob    = (u16*)alloc((size_t)H * H * 2);
    u16* W1b    = (u16*)alloc((size_t)Hh * H * 2);
    u16* W2b    = (u16*)alloc((size_t)H * Hh * 2);
    u16* Qb     = (u16*)alloc((size_t)M * H * 2);      // reused as hlnb
    u16* Kb     = (u16*)alloc((size_t)M * H * 2);      // reused as Gb
    u16* Vt     = (u16*)alloc((size_t)M * H * 2);
    u16* draftb = (u16*)alloc((size_t)M * H * 2);
    u16* Attb   = (u16*)alloc((size_t)M * H * 2);
    u16* hlnb = Qb;
    u16* Gb   = Kb;
    float* outp = (float*)d_out;

    CastArgs ca;
    ca.src[0] = x;  ca.dst[0] = Xb;                        ca.nblk[0] = (M * H / 8) / 256;
    ca.src[1] = Wq; ca.dst[1] = Wqkvb;                     ca.nblk[1] = (H * H / 8) / 256;
    ca.src[2] = Wk; ca.dst[2] = Wqkvb + (size_t)H * H;     ca.nblk[2] = (H * H / 8) / 256;
    ca.src[3] = Wv; ca.dst[3] = Wqkvb + (size_t)2 * H * H; ca.nblk[3] = (H * H / 8) / 256;
    ca.src[4] = Wo; ca.dst[4] = Wob;                       ca.nblk[4] = (H * H / 8) / 256;
    ca.src[5] = W1; ca.dst[5] = W1b;                       ca.nblk[5] = (Hh * H / 8) / 256;
    ca.src[6] = W2; ca.dst[6] = W2b;                       ca.nblk[6] = (H * Hh / 8) / 256;
    int totblk = 0;
    for (int i = 0; i < 7; ++i) totblk += ca.nblk[i];
    cast_all<<<dim3(totblk), dim3(256), 0, stream>>>(ca);

    // QKV: m97 128^2, grid 1536; XCD column-band swizzle (nrow=64)
    gemm97_qkv<<<dim3(1536), dim3(256), 0, stream>>>(
        Xb, Wqkvb, Qb, Kb, Vt, H, 64);

    attn_kernel<<<dim3(256), dim3(512), 0, stream>>>(Qb, Kb, Vt, Attb);

    // Wo: ring 4-barrier, grid 256, ncol=8; draftb = bf16(Xb + C)
    gemm_ring<1, 128><<<dim3(256), dim3(512), 0, stream>>>(
        Attb, Wob, nullptr, nullptr, Xb, draftb, nullptr, M, H, H, 8);

    ln_kernel<<<dim3(M), dim3(256), 0, stream>>>(draftb, lnw, lnb, hlnb);

    // W1: ring BN=64, grid 256, ncol=8; Gb = gelu(C + b1)
    gemm_ring<2, 64><<<dim3(256), dim3(512), 0, stream>>>(
        hlnb, W1b, Gb, b1, nullptr, nullptr, nullptr, M, Hh, H, 8);

    // W2: ring, grid 256, ncol=8, K=512; out = draftb + C + b2
    gemm_ring<3, 128><<<dim3(256), dim3(512), 0, stream>>>(
        Gb, W2b, nullptr, b2, nullptr, draftb, outp, M, H, Hh, 8);
}

// Round 16
// 164.006 us; speedup vs baseline: 1.0863x; 1.0863x over previous
//
#include <hip/hip_runtime.h>
#include <stdint.h>

typedef unsigned short u16;
typedef __bf16 bfx8 __attribute__((ext_vector_type(8)));
typedef float f32x4 __attribute__((ext_vector_type(4)));

__device__ __forceinline__ u16 f2bf(float x) {
    unsigned int u = __float_as_uint(x);
    u += 0x7fffu + ((u >> 16) & 1u);
    return (u16)(u >> 16);
}
__device__ __forceinline__ float bf2f(u16 v) {
    return __uint_as_float(((unsigned)v) << 16);
}

__device__ __forceinline__ void async16(const void* g, void* l) {
    __builtin_amdgcn_global_load_lds(
        (const __attribute__((address_space(1))) unsigned int*)(uintptr_t)g,
        (__attribute__((address_space(3))) unsigned int*)(unsigned int)(uintptr_t)l,
        16, 0, 0);
}

#define S_BARRIER() asm volatile("s_barrier" ::: "memory")
#define WAIT_VM6() asm volatile("s_waitcnt vmcnt(6)" ::: "memory")
#define WAIT_VM5() asm volatile("s_waitcnt vmcnt(5)" ::: "memory")
#define WAIT_VM0() asm volatile("s_waitcnt vmcnt(0)" ::: "memory")

// ---------------------------------------------------------------------------
// fused cast: 7 segments of f32 -> bf16, 8 elems/thread, one launch
// ---------------------------------------------------------------------------
struct CastArgs {
    const float* src[7];
    u16* dst[7];
    int nblk[7];
};
__global__ __launch_bounds__(256) void cast_all(CastArgs a) {
    int b = blockIdx.x, seg = 0;
    while (b >= a.nblk[seg]) { b -= a.nblk[seg]; ++seg; }
    int i = b * 256 + threadIdx.x;
    const float4* p = (const float4*)(a.src[seg] + (size_t)i * 8);
    float4 x = p[0], y = p[1];
    ushort4 o0, o1;
    o0.x = f2bf(x.x); o0.y = f2bf(x.y); o0.z = f2bf(x.z); o0.w = f2bf(x.w);
    o1.x = f2bf(y.x); o1.y = f2bf(y.y); o1.z = f2bf(y.z); o1.w = f2bf(y.w);
    ushort4* q = (ushort4*)(a.dst[seg] + (size_t)i * 8);
    q[0] = o0; q[1] = o1;
}

// ---------------------------------------------------------------------------
// m97-structure GEMM for QKV (measured best, reproduced r10/r13/r14:
// 60.8us @ 847 TF): 128x128 tile, BK=64, 256 threads = 4 waves (2Mx2N),
// single 32KB LDS, 2-barrier loop, XOR-8 swizzle both sides.
// ROW-BAND XCD swizzle (ncol=24): A panel 2MB L2-resident per XCD; r15's
// column-band variant streamed full A per XCD (FETCH 73->181MB, +29% dur).
// No r x c chunk of 192 blocks fits both panels in 4MB L2 ((r+c)*256KB
// >= 7MB) — row-band is the proven optimum.
// launch_bounds(256,4): VGPR 60. (256,5) forces VGPR 48 -> acc spill (r12).
// Epilogue: cols 0-1023 Q / 1024-2047 K / 2048-3071 V^T.
// ---------------------------------------------------------------------------
__global__ __launch_bounds__(256, 4)
void gemm97_qkv(const u16* __restrict__ A, const u16* __restrict__ Bw,
                u16* __restrict__ outq, u16* __restrict__ outk,
                u16* __restrict__ vt, int K, int ncol) {
    __shared__ __align__(1024) unsigned char lds[32768];
    const int t = threadIdx.x;
    const int lane = t & 63, w = t >> 6;
    const int laneR = lane & 15, laneK = lane >> 4;
    const int wr = w >> 1, wc = w & 1;
    const int b = blockIdx.x;
    const int cpx = gridDim.x >> 3;
    const int swz = (b & 7) * cpx + (b >> 3);
    const int row0 = (swz / ncol) * 128, col0 = (swz % ncol) * 128;
    const int nt = K >> 6;

    f32x4 acc[4][4] = {};

    const u16* srcA[4];
    const u16* srcB[4];
    unsigned dA[4], dB[4];
#pragma unroll
    for (int i = 0; i < 4; ++i) {
        int li = i * 256 + t;
        int row = li >> 3, ko = li & 7;
        int kos = (ko ^ (row & 7)) * 8;
        srcA[i] = A + (size_t)(row0 + row) * K + kos;
        srcB[i] = Bw + (size_t)(col0 + row) * K + kos;
        dA[i] = li * 16;
        dB[i] = 16384 + li * 16;
    }

    for (int tk = 0; tk < nt; ++tk) {
        const int o = tk * 64;
#pragma unroll
        for (int i = 0; i < 4; ++i) {
            async16(srcA[i] + o, lds + dA[i]);
            async16(srcB[i] + o, lds + dB[i]);
        }
        __syncthreads();
#pragma unroll
        for (int ks = 0; ks < 2; ++ks) {
            bfx8 af[4], bf[4];
#pragma unroll
            for (int m = 0; m < 4; ++m) {
                int r = wr * 64 + m * 16 + laneR;
                int ph = (ks * 4 + laneK) ^ (r & 7);
                af[m] = *(const bfx8*)(lds + r * 128 + ph * 16);
            }
#pragma unroll
            for (int n = 0; n < 4; ++n) {
                int r = wc * 64 + n * 16 + laneR;
                int ph = (ks * 4 + laneK) ^ (r & 7);
                bf[n] = *(const bfx8*)(lds + 16384 + r * 128 + ph * 16);
            }
#pragma unroll
            for (int m = 0; m < 4; ++m)
#pragma unroll
                for (int n = 0; n < 4; ++n)
                    acc[m][n] = __builtin_amdgcn_mfma_f32_16x16x32_bf16(
                        af[m], bf[n], acc[m][n], 0, 0, 0);
        }
        __syncthreads();
    }

#pragma unroll
    for (int m = 0; m < 4; ++m) {
        const int gr0 = row0 + wr * 64 + m * 16 + laneK * 4;
#pragma unroll
        for (int n = 0; n < 4; ++n) {
            const int gc = col0 + wc * 64 + n * 16 + laneR;
            if (col0 < 1024) {
#pragma unroll
                for (int r = 0; r < 4; ++r)
                    outq[(size_t)(gr0 + r) * 1024 + gc] = f2bf(acc[m][n][r]);
            } else if (col0 < 2048) {
#pragma unroll
                for (int r = 0; r < 4; ++r)
                    outk[(size_t)(gr0 + r) * 1024 + (gc - 1024)] = f2bf(acc[m][n][r]);
            } else {
                ushort4 o4;
                o4.x = f2bf(acc[m][n][0]); o4.y = f2bf(acc[m][n][1]);
                o4.z = f2bf(acc[m][n][2]); o4.w = f2bf(acc[m][n][3]);
                *(ushort4*)(vt + (((size_t)(gr0 >> 12)) * 1024 + (gc - 2048)) * 4096 +
                            (gr0 & 4095)) = o4;
            }
        }
    }
}

// ---------------------------------------------------------------------------
// RING GEMM (r8/r10 4-barrier variant, measured best for Wo/W1/W2):
// BM=256, BN=BNv(128|64), BK=64, 8 waves (4M x 2N), wave tile 64 x BNv/2.
// 3-deep LDS ring, depth-2 prefetch, counted vmcnt(6|5) folded into the
// ks1 end-barrier. XCD-chunked bijective 1D grid swizzle.
// EPI 1: draftb = bf16(bf2f(resb) + C)
// EPI 2 (BN=64): outb = bf16(gelu(C + bias))
// EPI 3: outf = bf2f(draftb) + C + bias
// ---------------------------------------------------------------------------
template <int EPI, int BNv>
__global__ __launch_bounds__(512, 2)
void gemm_ring(const u16* __restrict__ A, const u16* __restrict__ Bw,
               u16* __restrict__ outb, const float* __restrict__ bias,
               const u16* __restrict__ resb, u16* __restrict__ draftb,
               float* __restrict__ outf, int M, int N, int K, int ncol) {
    constexpr int NF = BNv / 32;
    constexpr int BU = BNv / 64;
    constexpr int TS = 32768 + BNv * 128;
    __shared__ __align__(1024) unsigned char lds[3 * TS];
    const int t = threadIdx.x;
    const int lane = t & 63, w = t >> 6;
    const int laneR = lane & 15, laneK = lane >> 4;
    const int wr = w >> 1, wc = w & 1;
    const int b = blockIdx.x;
    const int cpx = gridDim.x >> 3;
    const int swz = (b & 7) * cpx + (b >> 3);
    const int row0 = (swz / ncol) * 256, col0 = (swz % ncol) * BNv;
    const int nt = K >> 6;

    f32x4 acc[4][NF] = {};

    const u16* srcA[4];
    const u16* srcB[BU];
    unsigned dA[4], dB[BU];
#pragma unroll
    for (int i = 0; i < 4; ++i) {
        int li = i * 512 + t;
        int row = li >> 3, ko = li & 7;
        srcA[i] = A + (size_t)(row0 + row) * K + (ko ^ (row & 7)) * 8;
        dA[i] = li * 16;
    }
#pragma unroll
    for (int i = 0; i < BU; ++i) {
        int li = i * 512 + t;
        int row = li >> 3, ko = li & 7;
        srcB[i] = Bw + (size_t)(col0 + row) * K + (ko ^ (row & 7)) * 8;
        dB[i] = 32768 + li * 16;
    }

    auto stage = [&](int rb, int tk, int h) {
        unsigned char* base = lds + rb * TS;
        const int o = tk * 64;
        if (h == 0) {
            async16(srcA[0] + o, base + dA[0]);
            async16(srcA[1] + o, base + dA[1]);
            async16(srcB[0] + o, base + dB[0]);
        } else {
            async16(srcA[2] + o, base + dA[2]);
            async16(srcA[3] + o, base + dA[3]);
            if constexpr (BU == 2) async16(srcB[1] + o, base + dB[1]);
        }
    };

    stage(0, 0, 0); stage(0, 0, 1);
    stage(1, 1, 0); stage(1, 1, 1);
    if constexpr (BU == 2) { WAIT_VM6(); } else { WAIT_VM5(); }
    S_BARRIER();

    for (int tk = 0; tk < nt; ++tk) {
        unsigned char* bufA = lds + (tk % 3) * TS;
        unsigned char* bufB = bufA + 32768;
        const bool pf = (tk + 2 < nt);
        const int nb = (tk + 2) % 3;
#pragma unroll
        for (int ks = 0; ks < 2; ++ks) {
            bfx8 af[4], bf[NF];
#pragma unroll
            for (int m = 0; m < 4; ++m) {
                int r = wr * 64 + m * 16 + laneR;
                int phys = (ks * 4 + laneK) ^ (r & 7);
                af[m] = *(const bfx8*)(bufA + r * 128 + phys * 16);
            }
#pragma unroll
            for (int n = 0; n < NF; ++n) {
                int r = wc * (BNv / 2) + n * 16 + laneR;
                int phys = (ks * 4 + laneK) ^ (r & 7);
                bf[n] = *(const bfx8*)(bufB + r * 128 + phys * 16);
            }
            if (pf) stage(nb, tk + 2, ks);
            S_BARRIER();
            __builtin_amdgcn_s_setprio(1);
#pragma unroll
            for (int m = 0; m < 4; ++m)
#pragma unroll
                for (int n = 0; n < NF; ++n)
                    acc[m][n] = __builtin_amdgcn_mfma_f32_16x16x32_bf16(
                        af[m], bf[n], acc[m][n], 0, 0, 0);
            __builtin_amdgcn_s_setprio(0);
            if (ks == 1) {
                if (pf) {
                    if constexpr (BU == 2) { WAIT_VM6(); } else { WAIT_VM5(); }
                } else {
                    WAIT_VM0();
                }
            }
            S_BARRIER();
        }
    }

#pragma unroll
    for (int m = 0; m < 4; ++m) {
        const int gr0 = row0 + wr * 64 + m * 16 + laneK * 4;
#pragma unroll
        for (int n = 0; n < NF; ++n) {
            const int gc = col0 + wc * (BNv / 2) + n * 16 + laneR;
            if constexpr (EPI == 1) {
#pragma unroll
                for (int r = 0; r < 4; ++r) {
                    size_t idx = (size_t)(gr0 + r) * N + gc;
                    draftb[idx] = f2bf(bf2f(resb[idx]) + acc[m][n][r]);
                }
            } else if constexpr (EPI == 2) {
#pragma unroll
                for (int r = 0; r < 4; ++r) {
                    float xx = acc[m][n][r] + bias[gc];
                    outb[(size_t)(gr0 + r) * N + gc] =
                        f2bf(xx * 0.5f * (1.0f + erff(xx * 0.70710678118654752f)));
                }
            } else {
#pragma unroll
                for (int r = 0; r < 4; ++r) {
                    size_t idx = (size_t)(gr0 + r) * N + gc;
                    outf[idx] = bf2f(draftb[idx]) + acc[m][n][r] + bias[gc];
                }
            }
        }
    }
}

// ---------------------------------------------------------------------------
// banded attention: WINDOW=32, 32-query tiles, 64-key band [i0-32, i0+31]
// (r13 4-wave variant; r14's 8-wave restructure measured equal)
// ---------------------------------------------------------------------------
__global__ __launch_bounds__(256, 2)
void attn_kernel(const u16* __restrict__ Q, const u16* __restrict__ K,
                 const u16* __restrict__ vt, u16* __restrict__ O) {
    constexpr int H = 1024, S = 4096;
    const int t = threadIdx.x, lane = t & 63, w = t >> 6;
    const int laneR = lane & 15, laneK = lane >> 4;
    const int bb = blockIdx.x;
    const int tile = (bb & 7) * 32 + (bb >> 3);
    const int batch = tile >> 7;
    const int i0 = (tile & 127) * 32;
    const size_t base = (size_t)batch * S * H;

    __shared__ __align__(16) float S4[4][32][64];
    __shared__ __align__(16) u16 P[32][72];

    f32x4 sc[2][4] = {};
    for (int h = w * 256; h < w * 256 + 256; h += 32) {
        bfx8 qa[2];
#pragma unroll
        for (int m = 0; m < 2; ++m) {
            size_t row = (size_t)(i0 + m * 16 + laneR);
            qa[m] = *(const bfx8*)(Q + base + row * H + h + laneK * 8);
        }
        bfx8 kb[4];
#pragma unroll
        for (int n = 0; n < 4; ++n) {
            int j = i0 - 32 + n * 16 + laneR;
            int jc = j < 0 ? 0 : j;
            kb[n] = *(const bfx8*)(K + base + (size_t)jc * H + h + laneK * 8);
        }
#pragma unroll
        for (int m = 0; m < 2; ++m)
#pragma unroll
            for (int n = 0; n < 4; ++n)
                sc[m][n] = __builtin_amdgcn_mfma_f32_16x16x32_bf16(
                    qa[m], kb[n], sc[m][n], 0, 0, 0);
    }
#pragma unroll
    for (int m = 0; m < 2; ++m)
#pragma unroll
        for (int n = 0; n < 4; ++n)
#pragma unroll
            for (int r = 0; r < 4; ++r)
                S4[w][m * 16 + laneK * 4 + r][n * 16 + laneR] = sc[m][n][r];
    __syncthreads();

    {
        int q = t >> 3;
        int c0 = (t & 7) * 8;
        int lo = q + 1;
        if (32 - i0 > lo) lo = 32 - i0;
        int hi = q + 32;
        float vals[8];
        float mx = -1e30f;
#pragma unroll
        for (int c = 0; c < 8; ++c) {
            int cc = c0 + c;
            float v = (S4[0][q][cc] + S4[1][q][cc] + S4[2][q][cc] + S4[3][q][cc]) * 0.03125f;
            bool valid = (cc >= lo) && (cc <= hi);
            vals[c] = valid ? v : -1e30f;
            if (vals[c] > mx) mx = vals[c];
        }
#pragma unroll
        for (int d = 1; d < 8; d <<= 1) {
            float o = __shfl_xor(mx, d);
            if (o > mx) mx = o;
        }
        float sum = 0.f;
        float es[8];
#pragma unroll
        for (int c = 0; c < 8; ++c) {
            es[c] = (vals[c] > -1e29f) ? __expf(vals[c] - mx) : 0.f;
            sum += es[c];
        }
#pragma unroll
        for (int d = 1; d < 8; d <<= 1) sum += __shfl_xor(sum, d);
        float inv = 1.0f / sum;
#pragma unroll
        for (int c = 0; c < 8; ++c) P[q][c0 + c] = f2bf(es[c] * inv);
    }
    __syncthreads();

    for (int nc = 0; nc < 4; ++nc) {
        int ncol = w * 256 + nc * 64;
        f32x4 o[2][4] = {};
#pragma unroll
        for (int ks = 0; ks < 2; ++ks) {
            bfx8 pa[2];
#pragma unroll
            for (int m = 0; m < 2; ++m)
                pa[m] = *(const bfx8*)(&P[m * 16 + laneR][ks * 32 + laneK * 8]);
            int t0 = i0 - 32 + ks * 32 + laneK * 8;
            if (t0 < 0) t0 = 0;
#pragma unroll
            for (int n = 0; n < 4; ++n) {
                int c = ncol + n * 16 + laneR;
                bfx8 vb = *(const bfx8*)(vt + ((size_t)batch * 1024 + c) * 4096 + t0);
#pragma unroll
                for (int m = 0; m < 2; ++m)
                    o[m][n] = __builtin_amdgcn_mfma_f32_16x16x32_bf16(
                        pa[m], vb, o[m][n], 0, 0, 0);
            }
        }
#pragma unroll
        for (int m = 0; m < 2; ++m)
#pragma unroll
            for (int n = 0; n < 4; ++n)
#pragma unroll
                for (int r = 0; r < 4; ++r) {
                    size_t row = (size_t)(i0 + m * 16 + laneK * 4 + r);
                    O[base + row * H + ncol + n * 16 + laneR] = f2bf(o[m][n][r]);
                }
    }
}

// ---------------------------------------------------------------------------
// LayerNorm over H=1024, one block per row, bf16 in -> bf16 out
// ---------------------------------------------------------------------------
__global__ __launch_bounds__(256)
void ln_kernel(const u16* __restrict__ xb, const float* __restrict__ gw,
               const float* __restrict__ gb, u16* __restrict__ out) {
    const int row = blockIdx.x, t = threadIdx.x;
    const ushort4 dv = ((const ushort4*)(xb + (size_t)row * 1024))[t];
    float4 v;
    v.x = bf2f(dv.x); v.y = bf2f(dv.y); v.z = bf2f(dv.z); v.w = bf2f(dv.w);
    float s = v.x + v.y + v.z + v.w;
    float s2 = v.x * v.x + v.y * v.y + v.z * v.z + v.w * v.w;
#pragma unroll
    for (int d = 1; d < 64; d <<= 1) {
        s += __shfl_xor(s, d);
        s2 += __shfl_xor(s2, d);
    }
    __shared__ float red[8];
    int lane = t & 63, wv = t >> 6;
    if (lane == 0) { red[wv] = s; red[4 + wv] = s2; }
    __syncthreads();
    float S1 = red[0] + red[1] + red[2] + red[3];
    float S2 = red[4] + red[5] + red[6] + red[7];
    float mu = S1 * (1.0f / 1024.0f);
    float var = S2 * (1.0f / 1024.0f) - mu * mu;
    float rstd = rsqrtf(var + 1e-5f);
    const float4 wv4 = ((const float4*)gw)[t];
    const float4 bv4 = ((const float4*)gb)[t];
    ushort4 o;
    o.x = f2bf((v.x - mu) * rstd * wv4.x + bv4.x);
    o.y = f2bf((v.y - mu) * rstd * wv4.y + bv4.y);
    o.z = f2bf((v.z - mu) * rstd * wv4.z + bv4.z);
    o.w = f2bf((v.w - mu) * rstd * wv4.w + bv4.w);
    ((ushort4*)(out + (size_t)row * 1024))[t] = o;
}

// ---------------------------------------------------------------------------
extern "C" void kernel_launch(void* const* d_in, const int* in_sizes, int n_in,
                              void* d_out, int out_size, void* d_ws, size_t ws_size,
                              hipStream_t stream) {
    const float* x   = (const float*)d_in[0];
    const float* Wq  = (const float*)d_in[1];
    const float* Wk  = (const float*)d_in[2];
    const float* Wv  = (const float*)d_in[3];
    const float* Wo  = (const float*)d_in[4];
    const float* lnw = (const float*)d_in[5];
    const float* lnb = (const float*)d_in[6];
    const float* W1  = (const float*)d_in[7];
    const float* b1  = (const float*)d_in[8];
    const float* W2  = (const float*)d_in[9];
    const float* b2  = (const float*)d_in[10];
    (void)in_sizes; (void)n_in; (void)out_size; (void)ws_size;

    const int M = 8192, H = 1024, Hh = 512;

    char* ws = (char*)d_ws;
    size_t off = 0;
    auto alloc = [&](size_t bytes) {
        char* p = ws + off;
        off += (bytes + 255) & ~(size_t)255;
        return p;
    };
    u16* Xb     = (u16*)alloc((size_t)M * H * 2);      // residual for Wo
    u16* Wqkvb  = (u16*)alloc((size_t)3 * H * H * 2);
    u16* Wob    = (u16*)alloc((size_t)H * H * 2);
    u16* W1b    = (u16*)alloc((size_t)Hh * H * 2);
    u16* W2b    = (u16*)alloc((size_t)H * Hh * 2);
    u16* Qb     = (u16*)alloc((size_t)M * H * 2);      // reused as hlnb
    u16* Kb     = (u16*)alloc((size_t)M * H * 2);      // reused as Gb
    u16* Vt     = (u16*)alloc((size_t)M * H * 2);
    u16* draftb = (u16*)alloc((size_t)M * H * 2);
    u16* Attb   = (u16*)alloc((size_t)M * H * 2);
    u16* hlnb = Qb;
    u16* Gb   = Kb;
    float* outp = (float*)d_out;

    CastArgs ca;
    ca.src[0] = x;  ca.dst[0] = Xb;                        ca.nblk[0] = (M * H / 8) / 256;
    ca.src[1] = Wq; ca.dst[1] = Wqkvb;                     ca.nblk[1] = (H * H / 8) / 256;
    ca.src[2] = Wk; ca.dst[2] = Wqkvb + (size_t)H * H;     ca.nblk[2] = (H * H / 8) / 256;
    ca.src[3] = Wv; ca.dst[3] = Wqkvb + (size_t)2 * H * H; ca.nblk[3] = (H * H / 8) / 256;
    ca.src[4] = Wo; ca.dst[4] = Wob;                       ca.nblk[4] = (H * H / 8) / 256;
    ca.src[5] = W1; ca.dst[5] = W1b;                       ca.nblk[5] = (Hh * H / 8) / 256;
    ca.src[6] = W2; ca.dst[6] = W2b;                       ca.nblk[6] = (H * Hh / 8) / 256;
    int totblk = 0;
    for (int i = 0; i < 7; ++i) totblk += ca.nblk[i];
    cast_all<<<dim3(totblk), dim3(256), 0, stream>>>(ca);

    // QKV: m97 128^2, grid 1536, row-band XCD swizzle (ncol=24)
    gemm97_qkv<<<dim3(1536), dim3(256), 0, stream>>>(
        Xb, Wqkvb, Qb, Kb, Vt, H, 24);

    attn_kernel<<<dim3(256), dim3(256), 0, stream>>>(Qb, Kb, Vt, Attb);

    // Wo: ring 4-barrier, grid 256, ncol=8; draftb = bf16(Xb + C)
    gemm_ring<1, 128><<<dim3(256), dim3(512), 0, stream>>>(
        Attb, Wob, nullptr, nullptr, Xb, draftb, nullptr, M, H, H, 8);

    ln_kernel<<<dim3(M), dim3(256), 0, stream>>>(draftb, lnw, lnb, hlnb);

    // W1: ring BN=64, grid 256, ncol=8; Gb = gelu(C + b1)
    gemm_ring<2, 64><<<dim3(256), dim3(512), 0, stream>>>(
        hlnb, W1b, Gb, b1, nullptr, nullptr, nullptr, M, Hh, H, 8);

    // W2: ring, grid 256, ncol=8, K=512; out = draftb + C + b2
    gemm_ring<3, 128><<<dim3(256), dim3(512), 0, stream>>>(
        Gb, W2b, nullptr, b2, nullptr, draftb, outp, M, H, Hh, 8);
}